// Round 18
// baseline (59.645 us; speedup 1.0000x reference)
//
#include <hip/hip_runtime.h>

#define HW 56
#define NPIX 3136          // 56*56
#define CIN 256
#define OUTC 256
#define LOG2E 1.4426950408889634f

typedef unsigned short ushort_t;
typedef unsigned int uint_t;
typedef __attribute__((ext_vector_type(8))) short bf16x8;
typedef __attribute__((ext_vector_type(4))) float f32x4;
typedef __attribute__((ext_vector_type(2))) __fp16 half2v;   // cvt_pkrtz native type
typedef __attribute__((ext_vector_type(4))) _Float16 f16x4;  // mfma f16 operand

__device__ __forceinline__ ushort_t f2b(float f){
  uint_t u = __float_as_uint(f);
  u += 0x7fffu + ((u>>16)&1u);
  return (ushort_t)(u>>16);
}
__device__ __forceinline__ uint_t pkh2(float a, float b){
  union { half2v h; uint_t u; } pk;
  pk.h = __builtin_amdgcn_cvt_pkrtz(a, b);
  return pk.u;
}
__device__ __forceinline__ float h2lo(uint_t u){
  union { ushort_t s; __fp16 h; } c; c.s = (ushort_t)(u & 0xffffu); return (float)c.h;
}
__device__ __forceinline__ float h2hi(uint_t u){
  union { ushort_t s; __fp16 h; } c; c.s = (ushort_t)(u >> 16); return (float)c.h;
}
__device__ __forceinline__ float fdot2u(uint_t w, uint_t v, float acc){
  union { uint_t u; half2v h; } a, b; a.u = w; b.u = v;
  return __builtin_amdgcn_fdot2(a.h, b.h, acc, false);
}
__device__ __forceinline__ int refl(int v){ v = v<0 ? -v : v; return v>=HW ? 2*HW-2-v : v; }

// ---- workspace layout (4-byte element offsets unless noted) ----
// B_pk (bf16 MFMA-fragment-packed proj weights): ushort[81920] = elem [0,40960)
#define BF_OFF   40960      // bias[288] (pad 320)
#define CW1B_OFF 41280      // cw1 MFMA-B frags: uint[128] = [lane<64][q<2]
#define CW2B_OFF2 41536     // cw2 MFMA-B frags (log2e-scaled): uint[256] = [nf<2][lane<64][q<2]
#define CW2B_OFF 42048      // cw2b*log2e [32] (pad 64)
#define BNC_OFF  42112      // bn1s[16] bn1b[16] bn2s[16] bn2b[16]
#define P2T_OFF  42176      // P2t[57][256] fp32 = 14592 (rows 0-7 used by i-loop)
#define P2H_OFF  56768      // P2H[25][256] uint: half2(P2[tap 2p][c], P2[tap 2p+1][c]) = 25600
#define X1T_OFF  82368      // x1t[4][3136][16] fp32 (pixel-major)
#define X2T_OFF  283072     // x2t[4][3136][16] fp32 (pixel-major)
#define X3_BYTE_OFF 1935104 // x3h[4][3136][256] fp16 -> end 8,357,632 B (< proven 8.39 MB)

// ===================== K0: weight prep (unchanged) =====================
__global__ void k0_prep(const float* __restrict__ w1, const float* __restrict__ b1,
                        const float* __restrict__ w2, const float* __restrict__ b2,
                        const float* __restrict__ w3, const float* __restrict__ b3,
                        const float* __restrict__ g1, const float* __restrict__ be1,
                        const float* __restrict__ m1, const float* __restrict__ v1,
                        const float* __restrict__ cw1,
                        const float* __restrict__ g2, const float* __restrict__ be2,
                        const float* __restrict__ m2, const float* __restrict__ v2,
                        const float* __restrict__ cw2, const float* __restrict__ cw2b,
                        const float* __restrict__ p2,
                        float* __restrict__ ws)
{
  int idx = blockIdx.x*256 + threadIdx.x;
  if (idx < 81920){   // B_pk: k = kt*32+(l>>4)*8+j, n = nf*16+(l&15); n>=288 -> 0
    int j = idx & 7, l = (idx>>3)&63, t2 = idx>>9;
    int nf = t2 % 20, kt = t2 / 20;
    int k = kt*32 + (l>>4)*8 + j;
    int n = nf*16 + (l&15);
    float v = 0.f;
    if (n < 16)       v = w1[n*256 + k];
    else if (n < 32)  v = w2[(n-16)*256 + k];
    else if (n < 288) v = w3[(n-32)*256 + k];
    ((ushort_t*)ws)[idx] = f2b(v);
    return;
  }
  int j = idx - 81920;
  if (j < 288){ ws[BF_OFF+j] = (j<16 ? b1[j] : (j<32 ? b2[j-16] : b3[j-32])); return; }
  j -= 288;
  if (j < 32){ ws[BF_OFF+288+j] = 0.f; return; }
  j -= 32;
  if (j < 128){                          // cw1 B-frag: lane l holds n=l&15, k=(l>>4)*4+2q..+1
    int l = j>>1, q = j&1;
    int n = l & 15, k = ((l>>4)<<2) + 2*q;
    union { __fp16 h[2]; uint_t u; } cv;
    cv.h[0] = (__fp16)cw1[n*16 + k];
    cv.h[1] = (__fp16)cw1[n*16 + k+1];
    ((uint_t*)ws)[CW1B_OFF + j] = cv.u;
    return;
  }
  j -= 128;
  if (j < 256){                          // cw2 B-frags (log2e-scaled): nf in {0,1}
    int nf = j>>7, rem = j&127, l = rem>>1, q = rem&1;
    int n = nf*16 + (l & 15), k = ((l>>4)<<2) + 2*q;
    union { __fp16 h[2]; uint_t u; } cv;
    cv.h[0] = (__fp16)(cw2[n*16 + k]   * LOG2E);
    cv.h[1] = (__fp16)(cw2[n*16 + k+1] * LOG2E);
    ((uint_t*)ws)[CW2B_OFF2 + j] = cv.u;
    return;
  }
  j -= 256;
  if (j < 32){ ws[CW2B_OFF+j] = cw2b[j] * LOG2E; return; }
  j -= 32;
  if (j < 64){
    int set = j >> 4, c = j & 15;
    float o;
    if (set == 0){ o = g1[c] * rsqrtf(v1[c] + 1e-5f); }
    else if (set == 1){ float s = g1[c] * rsqrtf(v1[c] + 1e-5f); o = be1[c] - m1[c]*s; }
    else if (set == 2){ o = g2[c] * rsqrtf(v2[c] + 1e-5f); }
    else { float s = g2[c] * rsqrtf(v2[c] + 1e-5f); o = be2[c] - m2[c]*s; }
    ws[BNC_OFF+j] = o;
    return;
  }
  j -= 64;
  if (j < 14592){                        // P2t[i][g*8+o] = p2[(g*8+o)*57 + i]
    int i = j >> 8, rem = j & 255;
    ws[P2T_OFF + j] = p2[rem*57 + i];
    return;
  }
  j -= 14592;
  if (j < 25600){                        // P2H[p][c] = half2(row 8+2p, row 9+2p)
    int p = j >> 8, c = j & 255;
    union { __fp16 h[2]; uint_t u; } cv;
    cv.h[0] = (__fp16)p2[c*57 + 8 + 2*p];
    cv.h[1] = (2*p+1 < 49) ? (__fp16)p2[c*57 + 9 + 2*p] : (__fp16)0.f;
    ((uint_t*)ws)[P2H_OFF + j] = cv.u;
    return;
  }
}

// ===================== K1 v5: MFMA projection GEMM (unchanged) =====================
__global__ __launch_bounds__(256,4) void k1_proj(const float* __restrict__ x,
                                                 float* __restrict__ ws,
                                                 _Float16* __restrict__ x3h)
{
  __shared__ float xs[CIN*16];        // [c][px] fp32, 16 KB
  int t = threadIdx.x;
  int bid = blockIdx.x;               // 0..783
  int b = bid / 196, pp = (bid - b*196)*16;
  int wv = __builtin_amdgcn_readfirstlane(t >> 6);
  int lane = t & 63;

  { // stage: c = i*64 + (t>>2), px = (t&3)*4; lds float idx i*1024 + t*4 == c*16 + px
    const float* src = x + (size_t)b*CIN*NPIX + pp;
    int c0 = t >> 2;
    int po = (t & 3) * 4;
    #pragma unroll
    for (int i=0;i<4;i++){
      const float* gp = src + (size_t)(i*64 + c0)*NPIX + po;
      __builtin_amdgcn_global_load_lds(
          (const __attribute__((address_space(1))) void*)gp,
          (__attribute__((address_space(3))) void*)(xs + i*1024 + wv*256),
          16, 0, 0);
    }
  }
  __syncthreads();

  f32x4 acc[5];
  #pragma unroll
  for (int nf=0;nf<5;nf++){
    float bv = ws[BF_OFF + wv*80 + nf*16 + (lane&15)];
    acc[nf] = (f32x4){bv,bv,bv,bv};
  }

  const uint4* bpk = (const uint4*)ws;
  #pragma unroll 1
  for (int kt=0;kt<8;kt++){
    int abase = (kt*32 + ((lane>>4)<<3))*16 + (lane&15);
    union { uint_t u[4]; bf16x8 v; } ahi, alo;
    {
      float f[8];
      #pragma unroll
      for (int j=0;j<8;j++) f[j] = xs[abase + j*16];
      #pragma unroll
      for (int p=0;p<4;p++){
        uint_t u0 = __float_as_uint(f[2*p]), u1 = __float_as_uint(f[2*p+1]);
        uint_t h1 = u1 & 0xffff0000u;
        ahi.u[p] = (u0>>16) | h1;
        float l0 = f[2*p]   - __uint_as_float(u0 & 0xffff0000u);
        float l1 = f[2*p+1] - __uint_as_float(h1);
        alo.u[p] = (__float_as_uint(l0)>>16) | (__float_as_uint(l1) & 0xffff0000u);
      }
    }
    #pragma unroll
    for (int nf=0;nf<5;nf++){
      union { uint4 q; bf16x8 v; } bw;
      bw.q = bpk[(size_t)(kt*20 + wv*5 + nf)*64 + lane];
      acc[nf] = __builtin_amdgcn_mfma_f32_16x16x32_bf16(ahi.v, bw.v, acc[nf], 0,0,0);
      acc[nf] = __builtin_amdgcn_mfma_f32_16x16x32_bf16(alo.v, bw.v, acc[nf], 0,0,0);
    }
  }

  #pragma unroll
  for (int r=0;r<4;r++){
    int sp = pp + ((lane>>4)<<2) + r;
    #pragma unroll
    for (int nf=0;nf<5;nf++){
      int n = wv*80 + nf*16 + (lane&15);
      float val = acc[nf][r];
      if (n < 16){
        ws[X1T_OFF + (size_t)(b*NPIX + sp)*16 + n] = val;
      } else if (n < 32){
        ws[X2T_OFF + (size_t)(b*NPIX + sp)*16 + (n-16)] = val;
      } else if (n < 288){
        x3h[((size_t)b*NPIX + sp)*256 + (n-32)] = (_Float16)val;
      }
    }
  }
}

// ===================== K2: fused attention, transposed-w phase 4 =====================
// lgw: per-wave logits [g<32][27] packed fp16 tap-pairs.
// wT:  block-shared UNNORMALIZED w-pairs, [p<25][g<32][px<4] u32, p-stride 132 (pad).
// sA:  phase-1 scratch; overlaid AFTER the phase1->2 barrier by
//      agsT [i<8][g4<32][px<4] f32 (stride 132) + invs[px<4][g<32] at word 1056.
// RACE FIX (R17): agsT/invsL span OTHER waves' sA scratch -> all overlay writes must
// be ordered after ALL waves' phase-1 sA reads via __syncthreads().
__global__ __launch_bounds__(256,4) void k2_fused(const float* __restrict__ ws,
                                                  const _Float16* __restrict__ x3h,
                                                  float* __restrict__ out)
{
  __shared__ uint_t lgw[4*864];                        // 13824 B
  __shared__ __align__(16) uint_t wT[25*132];          // 13200 B
  __shared__ __align__(16) ushort_t sA[4*1280];        // 10240 B (phase1) / agsT+invs
  __shared__ int    gp_s[4*64];                        // 1024 B

  int tid = threadIdx.x;
  int bid0 = blockIdx.x;
  int bid = (bid0 & 7)*392 + (bid0 >> 3);     // XCD-contiguous pixel spans
  int b = bid / 784; int rem = bid - b*784;
  int row = rem / 14, xs4 = rem - row*14;
  int wv = __builtin_amdgcn_readfirstlane(tid >> 6);
  int lane = tid & 63;
  int y = row, x = xs4*4 + wv;
  int pix = y*HW + x;

  const float* bnc  = ws + BNC_OFF;
  const float* cw2b = ws + CW2B_OFF;
  uint_t* wvbase = lgw + wv*864;
  ushort_t* sAw = sA + wv*1280;
  float* agsT = (float*)sA;                   // overlay (valid after phase1->2 barrier)
  float* invsL = (float*)sA + 1056;           // [px][32]
  int lrow = lane & 15, lk4 = (lane>>4)<<2;

  // ---- phase 1: h1 (lane = tap) then MFMA MLP ----
  {
    int k = lane;
    int kk = k < 49 ? k : 48;
    int ki = kk / 7, kj = kk - ki*7;
    int gy = refl(y + ki - 3), gx = refl(x + kj - 3);
    int go = gy*HW + gx;
    gp_s[wv*64 + lane] = go << 9;       // byte offset into [pix][256] fp16 rows

    const float*  x1p = ws + X1T_OFF + (size_t)(b*NPIX + pix)*16;   // uniform -> s_load
    const float4* x2p = (const float4*)(ws + X2T_OFF + (size_t)(b*NPIX + go)*16);
    float4 v0 = x2p[0], v1 = x2p[1], v2 = x2p[2], v3 = x2p[3];
    float x2v[16] = {v0.x,v0.y,v0.z,v0.w, v1.x,v1.y,v1.z,v1.w,
                     v2.x,v2.y,v2.z,v2.w, v3.x,v3.y,v3.z,v3.w};
    float h1[16];
    #pragma unroll
    for (int c=0;c<16;c++){
      float d = x1p[c] - x2v[c];
      h1[c] = fmaxf(d*bnc[c] + bnc[16+c], 0.f);
    }
    // h1 -> sA [tap][c] f16 (row stride 20 f16 = 40 B)
    {
      uint2* dst = (uint2*)(sAw + lane*20);
      dst[0] = make_uint2(pkh2(h1[0],h1[1]),  pkh2(h1[2],h1[3]));
      dst[1] = make_uint2(pkh2(h1[4],h1[5]),  pkh2(h1[6],h1[7]));
      dst[2] = make_uint2(pkh2(h1[8],h1[9]),  pkh2(h1[10],h1[11]));
      dst[3] = make_uint2(pkh2(h1[12],h1[13]),pkh2(h1[14],h1[15]));
    }
    // B fragments (L2-hot)
    union { uint2 u; f16x4 h; } B1, B20, B21;
    B1.u  = ((const uint2*)((const uint_t*)ws + CW1B_OFF))[lane];
    B20.u = ((const uint2*)((const uint_t*)ws + CW2B_OFF2))[lane];
    B21.u = ((const uint2*)((const uint_t*)ws + CW2B_OFF2))[64 + lane];

    // GEMM1: t = relu(bn2(h1 @ cw1^T))
    float bs2 = bnc[32+lrow], bb2 = bnc[48+lrow];
    #pragma unroll
    for (int m=0;m<4;m++){
      union { uint2 u; f16x4 h; } A;
      A.u = *(const uint2*)(sAw + (m*16+lrow)*20 + lk4);
      f32x4 d = __builtin_amdgcn_mfma_f32_16x16x16f16(A.h, B1.h, (f32x4){0.f,0.f,0.f,0.f}, 0,0,0);
      #pragma unroll
      for (int r=0;r<4;r++){
        float tv = fmaxf(d[r]*bs2 + bb2, 0.f);
        union { __fp16 h; ushort_t s; } th; th.h = (__fp16)tv;
        sAw[(m*16 + lk4 + r)*20 + lrow] = th.s;
      }
    }
    // GEMM2: logits(log2-scaled) = t @ (cw2*log2e)^T + cw2b*log2e; packed tap-pairs [g][27]
    float bg0 = cw2b[lrow], bg1 = cw2b[16+lrow];
    #pragma unroll
    for (int m=0;m<4;m++){
      union { uint2 u; f16x4 h; } A2;
      A2.u = *(const uint2*)(sAw + (m*16+lrow)*20 + lk4);
      f32x4 d0 = __builtin_amdgcn_mfma_f32_16x16x16f16(A2.h, B20.h, (f32x4){bg0,bg0,bg0,bg0}, 0,0,0);
      f32x4 d1 = __builtin_amdgcn_mfma_f32_16x16x16f16(A2.h, B21.h, (f32x4){bg1,bg1,bg1,bg1}, 0,0,0);
      int pq = m*8 + ((lane>>4)<<1);         // tap-pair index of d[0],d[1]
      uint_t p01 = pkh2(d0[0], d0[1]), p23 = pkh2(d0[2], d0[3]);
      uint_t q01 = pkh2(d1[0], d1[1]), q23 = pkh2(d1[2], d1[3]);
      if (pq < 25){
        wvbase[lrow*27 + pq]      = p01;
        wvbase[(16+lrow)*27 + pq] = q01;
      }
      if (pq+1 < 25){
        wvbase[lrow*27 + pq+1]      = p23;
        wvbase[(16+lrow)*27 + pq+1] = q23;
      }
    }
  }

  __syncthreads();   // RACE FIX: all phase-1 sA reads complete before overlay writes

  // ---- phase 2: softmax (log2 space); write UNNORMALIZED w-pairs transposed + inv ----
  {
    int half = lane >> 5, g = lane & 31;
    const uint_t* lgp = wvbase + g*27;
    float e[25];
    float M = -3.0e38f;
    if (half == 0){
      #pragma unroll
      for (int j=0;j<12;j++){
        uint_t u = lgp[j];
        e[2*j]   = h2lo(u);
        e[2*j+1] = h2hi(u);
      }
      e[24] = h2lo(lgp[12]);
      #pragma unroll
      for (int i=0;i<25;i++) M = fmaxf(M, e[i]);
    } else {
      e[0] = h2hi(lgp[12]);
      #pragma unroll
      for (int j=0;j<11;j++){
        uint_t u = lgp[13+j];
        e[1+2*j] = h2lo(u);
        e[2+2*j] = h2hi(u);
      }
      e[23] = h2lo(lgp[24]);
      e[24] = 0.f;
      #pragma unroll
      for (int i=0;i<24;i++) M = fmaxf(M, e[i]);
    }
    M = fmaxf(M, __shfl_xor(M, 32, 64));
    float s = 0.f;
    #pragma unroll
    for (int i=0;i<25;i++){
      if (half == 0 || i < 24){
        e[i] = exp2f(e[i] - M);
        s += e[i];
      }
    }
    s += __shfl_xor(s, 32, 64);
    if (half == 0) invsL[wv*32 + g] = 1.f / s;
    float other = __shfl_xor(half ? e[0] : e[24], 32, 64);  // half0 gets tap25
    if (half == 0){
      #pragma unroll
      for (int p=0;p<12;p++) wT[p*132 + g*4 + wv] = pkh2(e[2*p], e[2*p+1]);
      wT[12*132 + g*4 + wv] = pkh2(e[24], other);           // pair 12 = taps 24,25
    } else {
      #pragma unroll
      for (int q=0;q<11;q++) wT[(13+q)*132 + g*4 + wv] = pkh2(e[1+2*q], e[2+2*q]);
      wT[24*132 + g*4 + wv] = pkh2(e[23], 0.f);             // pair 24 = taps 48,(49=0)
    }
  }

  // ---- phase 3: aggregation (lane owns channels 4L..4L+3), unnormalized w + inv scale ----
  {
    int g_ = lane >> 1;
    int c0 = lane * 4;
    const int* gpp = gp_s + wv*64;
    float a0=0.f,a1=0.f,a2=0.f,a3=0.f;
    const char* xbb = (const char*)(x3h + (size_t)b*NPIX*256) + c0*2;
    #pragma unroll 5
    for (int p=0;p<25;p++){
      uint_t wu = wT[p*132 + g_*4 + wv];
      float w0 = h2lo(wu), w1 = h2hi(wu);
      int o0 = gpp[2*p], o1 = gpp[2*p+1];
      union { uint2 u; _Float16 h[4]; } d0, d1;
      d0.u = *(const uint2*)(xbb + o0);
      d1.u = *(const uint2*)(xbb + o1);
      a0 += w0*(float)d0.h[0] + w1*(float)d1.h[0];
      a1 += w0*(float)d0.h[1] + w1*(float)d1.h[1];
      a2 += w0*(float)d0.h[2] + w1*(float)d1.h[2];
      a3 += w0*(float)d0.h[3] + w1*(float)d1.h[3];
    }
    float inv = invsL[wv*32 + g_];
    a0 *= inv; a1 *= inv; a2 *= inv; a3 *= inv;
    // agsT[i][g4][px]: i = c0>>5 = lane>>3, g4 = (c0&31) = (lane&7)*4 .. +3
    int ii = lane >> 3, gb = (lane & 7) * 4;
    float* dst = agsT + ii*132 + gb*4 + wv;
    dst[0] = a0; dst[4] = a1; dst[8] = a2; dst[12] = a3;
  }
  __syncthreads();

  // ---- phase 4: position2, BLOCK-WIDE; b128 broadcast reads of wT/agsT ----
  {
    int c = tid, g4 = c >> 3;
    const float* P2 = ws + P2T_OFF;
    const uint_t* P2H = (const uint_t*)ws + P2H_OFF;
    float r0=0.f, r1=0.f, r2=0.f, r3=0.f;
    #pragma unroll
    for (int i=0;i<8;i++){
      f32x4 av = *(const f32x4*)(agsT + i*132 + g4*4);      // 4 pixels, broadcast x8
      float pv = P2[i*256 + c];
      r0 += av[0]*pv; r1 += av[1]*pv; r2 += av[2]*pv; r3 += av[3]*pv;
    }
    float t0=0.f, t1=0.f, t2=0.f, t3=0.f;
    #pragma unroll 5
    for (int p=0;p<25;p++){
      uint4 wq = *(const uint4*)(wT + p*132 + g4*4);        // 4 pixels' packed pairs
      uint_t ph = P2H[p*256 + c];
      t0 = fdot2u(wq.x, ph, t0);
      t1 = fdot2u(wq.y, ph, t1);
      t2 = fdot2u(wq.z, ph, t2);
      t3 = fdot2u(wq.w, ph, t3);
    }
    r0 += t0 * invsL[0*32 + g4];
    r1 += t1 * invsL[1*32 + g4];
    r2 += t2 * invsL[2*32 + g4];
    r3 += t3 * invsL[3*32 + g4];
    int pix0 = y*HW + xs4*4;
    *(float4*)(out + ((size_t)(b*256 + c))*NPIX + pix0) = make_float4(r0,r1,r2,r3);
  }
}

// ===================== launch =====================
extern "C" void kernel_launch(void* const* d_in, const int* in_sizes, int n_in,
                              void* d_out, int out_size, void* d_ws, size_t ws_size,
                              hipStream_t stream) {
  const float* x    = (const float*)d_in[0];
  const float* w1   = (const float*)d_in[1];
  const float* b1   = (const float*)d_in[2];
  const float* w2   = (const float*)d_in[3];
  const float* b2   = (const float*)d_in[4];
  const float* w3   = (const float*)d_in[5];
  const float* b3   = (const float*)d_in[6];
  const float* g1   = (const float*)d_in[7];
  const float* be1  = (const float*)d_in[8];
  const float* m1   = (const float*)d_in[9];
  const float* v1   = (const float*)d_in[10];
  const float* cw1  = (const float*)d_in[11];
  const float* g2   = (const float*)d_in[12];
  const float* be2  = (const float*)d_in[13];
  const float* m2   = (const float*)d_in[14];
  const float* v2   = (const float*)d_in[15];
  const float* cw2  = (const float*)d_in[16];
  const float* cw2b = (const float*)d_in[17];
  const float* p2   = (const float*)d_in[18];

  float* wsf = (float*)d_ws;
  _Float16* x3h = (_Float16*)((char*)d_ws + X3_BYTE_OFF);
  float* o = (float*)d_out;

  k0_prep<<<481, 256, 0, stream>>>(w1,b1,w2,b2,w3,b3,g1,be1,m1,v1,cw1,g2,be2,m2,v2,cw2,cw2b,p2,wsf);
  k1_proj<<<784, 256, 0, stream>>>(x, wsf, x3h);
  k2_fused<<<3136, 256, 0, stream>>>(wsf, x3h, o);
}

// Round 19
// 56.396 us; speedup vs baseline: 1.0576x; 1.0576x over previous
//
#include <hip/hip_runtime.h>

#define HW 56
#define NPIX 3136          // 56*56
#define CIN 256
#define OUTC 256
#define LOG2E 1.4426950408889634f

typedef unsigned short ushort_t;
typedef unsigned int uint_t;
typedef __attribute__((ext_vector_type(8))) short bf16x8;
typedef __attribute__((ext_vector_type(4))) float f32x4;
typedef __attribute__((ext_vector_type(2))) __fp16 half2v;   // cvt_pkrtz native type
typedef __attribute__((ext_vector_type(4))) _Float16 f16x4;  // mfma f16 operand

__device__ __forceinline__ ushort_t f2b(float f){
  uint_t u = __float_as_uint(f);
  u += 0x7fffu + ((u>>16)&1u);
  return (ushort_t)(u>>16);
}
__device__ __forceinline__ uint_t pkh2(float a, float b){
  union { half2v h; uint_t u; } pk;
  pk.h = __builtin_amdgcn_cvt_pkrtz(a, b);
  return pk.u;
}
__device__ __forceinline__ float h2lo(uint_t u){
  union { ushort_t s; __fp16 h; } c; c.s = (ushort_t)(u & 0xffffu); return (float)c.h;
}
__device__ __forceinline__ float h2hi(uint_t u){
  union { ushort_t s; __fp16 h; } c; c.s = (ushort_t)(u >> 16); return (float)c.h;
}
__device__ __forceinline__ float fdot2u(uint_t w, uint_t v, float acc){
  union { uint_t u; half2v h; } a, b; a.u = w; b.u = v;
  return __builtin_amdgcn_fdot2(a.h, b.h, acc, false);
}
__device__ __forceinline__ int refl(int v){ v = v<0 ? -v : v; return v>=HW ? 2*HW-2-v : v; }

// ---- workspace layout (4-byte element offsets unless noted) ----
// B_pk (bf16 MFMA-fragment-packed proj weights): ushort[81920] = elem [0,40960)
#define BF_OFF   40960      // bias[288] (pad 320)
#define CW1B_OFF 41280      // cw1 MFMA-B frags: uint[128] = [lane<64][q<2]
#define CW2B_OFF2 41536     // cw2 MFMA-B frags (log2e-scaled): uint[256] = [nf<2][lane<64][q<2]
#define CW2B_OFF 42048      // cw2b*log2e [32] (pad 64)
#define BNC_OFF  42112      // bn1s[16] bn1b[16] bn2s[16] bn2b[16]
#define P2T_OFF  42176      // P2t[57][256] fp32 = 14592 (rows 0-7 used by i-loop)
#define P2H_OFF  56768      // P2H[25][256] uint: half2(P2[tap 2p][c], P2[tap 2p+1][c]) = 25600
#define X1T_OFF  82368      // x1t[4][3136][16] fp32 (pixel-major)
#define X2T_OFF  283072     // x2t[4][3136][16] fp32 (pixel-major)
#define X3_BYTE_OFF 1935104 // x3h[4][3136][256] fp16 -> end 8,357,632 B (< proven 8.39 MB)

// ===================== K0: weight prep (R16-identical) =====================
__global__ void k0_prep(const float* __restrict__ w1, const float* __restrict__ b1,
                        const float* __restrict__ w2, const float* __restrict__ b2,
                        const float* __restrict__ w3, const float* __restrict__ b3,
                        const float* __restrict__ g1, const float* __restrict__ be1,
                        const float* __restrict__ m1, const float* __restrict__ v1,
                        const float* __restrict__ cw1,
                        const float* __restrict__ g2, const float* __restrict__ be2,
                        const float* __restrict__ m2, const float* __restrict__ v2,
                        const float* __restrict__ cw2, const float* __restrict__ cw2b,
                        const float* __restrict__ p2,
                        float* __restrict__ ws)
{
  int idx = blockIdx.x*256 + threadIdx.x;
  if (idx < 81920){   // B_pk: k = kt*32+(l>>4)*8+j, n = nf*16+(l&15); n>=288 -> 0
    int j = idx & 7, l = (idx>>3)&63, t2 = idx>>9;
    int nf = t2 % 20, kt = t2 / 20;
    int k = kt*32 + (l>>4)*8 + j;
    int n = nf*16 + (l&15);
    float v = 0.f;
    if (n < 16)       v = w1[n*256 + k];
    else if (n < 32)  v = w2[(n-16)*256 + k];
    else if (n < 288) v = w3[(n-32)*256 + k];
    ((ushort_t*)ws)[idx] = f2b(v);
    return;
  }
  int j = idx - 81920;
  if (j < 288){ ws[BF_OFF+j] = (j<16 ? b1[j] : (j<32 ? b2[j-16] : b3[j-32])); return; }
  j -= 288;
  if (j < 32){ ws[BF_OFF+288+j] = 0.f; return; }
  j -= 32;
  if (j < 128){                          // cw1 B-frag: lane l holds n=l&15, k=(l>>4)*4+2q..+1
    int l = j>>1, q = j&1;
    int n = l & 15, k = ((l>>4)<<2) + 2*q;
    union { __fp16 h[2]; uint_t u; } cv;
    cv.h[0] = (__fp16)cw1[n*16 + k];
    cv.h[1] = (__fp16)cw1[n*16 + k+1];
    ((uint_t*)ws)[CW1B_OFF + j] = cv.u;
    return;
  }
  j -= 128;
  if (j < 256){                          // cw2 B-frags (log2e-scaled): nf in {0,1}
    int nf = j>>7, rem = j&127, l = rem>>1, q = rem&1;
    int n = nf*16 + (l & 15), k = ((l>>4)<<2) + 2*q;
    union { __fp16 h[2]; uint_t u; } cv;
    cv.h[0] = (__fp16)(cw2[n*16 + k]   * LOG2E);
    cv.h[1] = (__fp16)(cw2[n*16 + k+1] * LOG2E);
    ((uint_t*)ws)[CW2B_OFF2 + j] = cv.u;
    return;
  }
  j -= 256;
  if (j < 32){ ws[CW2B_OFF+j] = cw2b[j] * LOG2E; return; }
  j -= 32;
  if (j < 64){
    int set = j >> 4, c = j & 15;
    float o;
    if (set == 0){ o = g1[c] * rsqrtf(v1[c] + 1e-5f); }
    else if (set == 1){ float s = g1[c] * rsqrtf(v1[c] + 1e-5f); o = be1[c] - m1[c]*s; }
    else if (set == 2){ o = g2[c] * rsqrtf(v2[c] + 1e-5f); }
    else { float s = g2[c] * rsqrtf(v2[c] + 1e-5f); o = be2[c] - m2[c]*s; }
    ws[BNC_OFF+j] = o;
    return;
  }
  j -= 64;
  if (j < 14592){                        // P2t[i][g*8+o] = p2[(g*8+o)*57 + i]
    int i = j >> 8, rem = j & 255;
    ws[P2T_OFF + j] = p2[rem*57 + i];
    return;
  }
  j -= 14592;
  if (j < 25600){                        // P2H[p][c] = half2(row 8+2p, row 9+2p)
    int p = j >> 8, c = j & 255;
    union { __fp16 h[2]; uint_t u; } cv;
    cv.h[0] = (__fp16)p2[c*57 + 8 + 2*p];
    cv.h[1] = (2*p+1 < 49) ? (__fp16)p2[c*57 + 9 + 2*p] : (__fp16)0.f;
    ((uint_t*)ws)[P2H_OFF + j] = cv.u;
    return;
  }
}

// ===================== K1 v5: MFMA projection GEMM (R16-identical) =====================
__global__ __launch_bounds__(256,4) void k1_proj(const float* __restrict__ x,
                                                 float* __restrict__ ws,
                                                 _Float16* __restrict__ x3h)
{
  __shared__ float xs[CIN*16];        // [c][px] fp32, 16 KB
  int t = threadIdx.x;
  int bid = blockIdx.x;               // 0..783
  int b = bid / 196, pp = (bid - b*196)*16;
  int wv = __builtin_amdgcn_readfirstlane(t >> 6);
  int lane = t & 63;

  { // stage: c = i*64 + (t>>2), px = (t&3)*4; lds float idx i*1024 + t*4 == c*16 + px
    const float* src = x + (size_t)b*CIN*NPIX + pp;
    int c0 = t >> 2;
    int po = (t & 3) * 4;
    #pragma unroll
    for (int i=0;i<4;i++){
      const float* gp = src + (size_t)(i*64 + c0)*NPIX + po;
      __builtin_amdgcn_global_load_lds(
          (const __attribute__((address_space(1))) void*)gp,
          (__attribute__((address_space(3))) void*)(xs + i*1024 + wv*256),
          16, 0, 0);
    }
  }
  __syncthreads();

  f32x4 acc[5];
  #pragma unroll
  for (int nf=0;nf<5;nf++){
    float bv = ws[BF_OFF + wv*80 + nf*16 + (lane&15)];
    acc[nf] = (f32x4){bv,bv,bv,bv};
  }

  const uint4* bpk = (const uint4*)ws;
  #pragma unroll 1
  for (int kt=0;kt<8;kt++){
    int abase = (kt*32 + ((lane>>4)<<3))*16 + (lane&15);
    union { uint_t u[4]; bf16x8 v; } ahi, alo;
    {
      float f[8];
      #pragma unroll
      for (int j=0;j<8;j++) f[j] = xs[abase + j*16];
      #pragma unroll
      for (int p=0;p<4;p++){
        uint_t u0 = __float_as_uint(f[2*p]), u1 = __float_as_uint(f[2*p+1]);
        uint_t h1 = u1 & 0xffff0000u;
        ahi.u[p] = (u0>>16) | h1;
        float l0 = f[2*p]   - __uint_as_float(u0 & 0xffff0000u);
        float l1 = f[2*p+1] - __uint_as_float(h1);
        alo.u[p] = (__float_as_uint(l0)>>16) | (__float_as_uint(l1) & 0xffff0000u);
      }
    }
    #pragma unroll
    for (int nf=0;nf<5;nf++){
      union { uint4 q; bf16x8 v; } bw;
      bw.q = bpk[(size_t)(kt*20 + wv*5 + nf)*64 + lane];
      acc[nf] = __builtin_amdgcn_mfma_f32_16x16x32_bf16(ahi.v, bw.v, acc[nf], 0,0,0);
      acc[nf] = __builtin_amdgcn_mfma_f32_16x16x32_bf16(alo.v, bw.v, acc[nf], 0,0,0);
    }
  }

  #pragma unroll
  for (int r=0;r<4;r++){
    int sp = pp + ((lane>>4)<<2) + r;
    #pragma unroll
    for (int nf=0;nf<5;nf++){
      int n = wv*80 + nf*16 + (lane&15);
      float val = acc[nf][r];
      if (n < 16){
        ws[X1T_OFF + (size_t)(b*NPIX + sp)*16 + n] = val;
      } else if (n < 32){
        ws[X2T_OFF + (size_t)(b*NPIX + sp)*16 + (n-16)] = val;
      } else if (n < 288){
        x3h[((size_t)b*NPIX + sp)*256 + (n-32)] = (_Float16)val;
      }
    }
  }
}

// ===================== K2: fused attention (R16 structure + full-unroll ph3/ph4) =====================
// lgw: per-wave logits [g<32][27] packed fp16 tap-pairs, overlaid after softmax with
// NORMALIZED w-pairs [25][33] (odd strides -> conflict-free; proven R13/R15/R16).
// sA: [64][20] f16 phase-1 scratch, overlaid per-wave by ags (float[256]) in phase 3 —
// wave-private overlay, safe by program order (R16-proven; R17's block-spanning overlay raced).
__global__ __launch_bounds__(256,6) void k2_fused(const float* __restrict__ ws,
                                                  const _Float16* __restrict__ x3h,
                                                  float* __restrict__ out)
{
  __shared__ uint_t lgw[4*864];                        // 13824 B
  __shared__ __align__(16) ushort_t sA[4*1280];        // 10240 B (phase1) / ags (phase3+)
  __shared__ int    gp_s[4*64];                        // 1024 B

  int tid = threadIdx.x;
  int bid0 = blockIdx.x;
  int bid = (bid0 & 7)*392 + (bid0 >> 3);     // XCD-contiguous pixel spans
  int b = bid / 784; int rem = bid - b*784;
  int row = rem / 14, xs4 = rem - row*14;
  int wv = __builtin_amdgcn_readfirstlane(tid >> 6);
  int lane = tid & 63;
  int y = row, x = xs4*4 + wv;
  int pix = y*HW + x;

  const float* bnc  = ws + BNC_OFF;
  const float* cw2b = ws + CW2B_OFF;
  uint_t* wvbase = lgw + wv*864;
  ushort_t* sAw = sA + wv*1280;
  int lrow = lane & 15, lk4 = (lane>>4)<<2;

  // ---- phase 1: h1 (lane = tap) then MFMA MLP ----
  {
    int k = lane;
    int kk = k < 49 ? k : 48;
    int ki = kk / 7, kj = kk - ki*7;
    int gy = refl(y + ki - 3), gx = refl(x + kj - 3);
    int go = gy*HW + gx;
    gp_s[wv*64 + lane] = go << 9;       // byte offset into [pix][256] fp16 rows

    const float*  x1p = ws + X1T_OFF + (size_t)(b*NPIX + pix)*16;   // uniform -> s_load
    const float4* x2p = (const float4*)(ws + X2T_OFF + (size_t)(b*NPIX + go)*16);
    float4 v0 = x2p[0], v1 = x2p[1], v2 = x2p[2], v3 = x2p[3];
    float x2v[16] = {v0.x,v0.y,v0.z,v0.w, v1.x,v1.y,v1.z,v1.w,
                     v2.x,v2.y,v2.z,v2.w, v3.x,v3.y,v3.z,v3.w};
    float h1[16];
    #pragma unroll
    for (int c=0;c<16;c++){
      float d = x1p[c] - x2v[c];
      h1[c] = fmaxf(d*bnc[c] + bnc[16+c], 0.f);
    }
    // h1 -> sA [tap][c] f16 (row stride 20 f16 = 40 B)
    {
      uint2* dst = (uint2*)(sAw + lane*20);
      dst[0] = make_uint2(pkh2(h1[0],h1[1]),  pkh2(h1[2],h1[3]));
      dst[1] = make_uint2(pkh2(h1[4],h1[5]),  pkh2(h1[6],h1[7]));
      dst[2] = make_uint2(pkh2(h1[8],h1[9]),  pkh2(h1[10],h1[11]));
      dst[3] = make_uint2(pkh2(h1[12],h1[13]),pkh2(h1[14],h1[15]));
    }
    // B fragments (L2-hot)
    union { uint2 u; f16x4 h; } B1, B20, B21;
    B1.u  = ((const uint2*)((const uint_t*)ws + CW1B_OFF))[lane];
    B20.u = ((const uint2*)((const uint_t*)ws + CW2B_OFF2))[lane];
    B21.u = ((const uint2*)((const uint_t*)ws + CW2B_OFF2))[64 + lane];

    // GEMM1: t = relu(bn2(h1 @ cw1^T))
    float bs2 = bnc[32+lrow], bb2 = bnc[48+lrow];
    #pragma unroll
    for (int m=0;m<4;m++){
      union { uint2 u; f16x4 h; } A;
      A.u = *(const uint2*)(sAw + (m*16+lrow)*20 + lk4);
      f32x4 d = __builtin_amdgcn_mfma_f32_16x16x16f16(A.h, B1.h, (f32x4){0.f,0.f,0.f,0.f}, 0,0,0);
      #pragma unroll
      for (int r=0;r<4;r++){
        float tv = fmaxf(d[r]*bs2 + bb2, 0.f);
        union { __fp16 h; ushort_t s; } th; th.h = (__fp16)tv;
        sAw[(m*16 + lk4 + r)*20 + lrow] = th.s;
      }
    }
    // GEMM2: logits(log2-scaled) = t @ (cw2*log2e)^T + cw2b*log2e; packed tap-pairs [g][27]
    float bg0 = cw2b[lrow], bg1 = cw2b[16+lrow];
    #pragma unroll
    for (int m=0;m<4;m++){
      union { uint2 u; f16x4 h; } A2;
      A2.u = *(const uint2*)(sAw + (m*16+lrow)*20 + lk4);
      f32x4 d0 = __builtin_amdgcn_mfma_f32_16x16x16f16(A2.h, B20.h, (f32x4){bg0,bg0,bg0,bg0}, 0,0,0);
      f32x4 d1 = __builtin_amdgcn_mfma_f32_16x16x16f16(A2.h, B21.h, (f32x4){bg1,bg1,bg1,bg1}, 0,0,0);
      int pq = m*8 + ((lane>>4)<<1);         // tap-pair index of d[0],d[1]
      uint_t p01 = pkh2(d0[0], d0[1]), p23 = pkh2(d0[2], d0[3]);
      uint_t q01 = pkh2(d1[0], d1[1]), q23 = pkh2(d1[2], d1[3]);
      if (pq < 25){
        wvbase[lrow*27 + pq]      = p01;
        wvbase[(16+lrow)*27 + pq] = q01;
      }
      if (pq+1 < 25){
        wvbase[lrow*27 + pq+1]      = p23;
        wvbase[(16+lrow)*27 + pq+1] = q23;
      }
    }
  }

  // ---- phase 2: softmax over 49 taps (log2 space, exp2); write packed NORMALIZED w-pairs ----
  {
    int half = lane >> 5, g = lane & 31;
    const uint_t* lgp = wvbase + g*27;
    float e[25];
    float M = -3.0e38f;
    if (half == 0){
      #pragma unroll
      for (int j=0;j<12;j++){
        uint_t u = lgp[j];
        e[2*j]   = h2lo(u);
        e[2*j+1] = h2hi(u);
      }
      e[24] = h2lo(lgp[12]);
      #pragma unroll
      for (int i=0;i<25;i++) M = fmaxf(M, e[i]);
    } else {
      e[0] = h2hi(lgp[12]);
      #pragma unroll
      for (int j=0;j<11;j++){
        uint_t u = lgp[13+j];
        e[1+2*j] = h2lo(u);
        e[2+2*j] = h2hi(u);
      }
      e[23] = h2lo(lgp[24]);
      e[24] = 0.f;
      #pragma unroll
      for (int i=0;i<24;i++) M = fmaxf(M, e[i]);
    }
    M = fmaxf(M, __shfl_xor(M, 32, 64));
    float s = 0.f;
    #pragma unroll
    for (int i=0;i<25;i++){
      if (half == 0 || i < 24){
        e[i] = exp2f(e[i] - M);
        s += e[i];
      }
    }
    s += __shfl_xor(s, 32, 64);
    float inv = 1.f / s;
    #pragma unroll
    for (int i=0;i<25;i++){
      if (half == 0 || i < 24) e[i] *= inv;
    }
    float other = __shfl_xor(half ? e[0] : e[24], 32, 64);  // half0 gets w25
    if (half == 0){
      #pragma unroll
      for (int p=0;p<12;p++) wvbase[p*33 + g] = pkh2(e[2*p], e[2*p+1]);
      wvbase[12*33 + g] = pkh2(e[24], other);               // pair 12 = taps 24,25
    } else {
      #pragma unroll
      for (int q=0;q<11;q++) wvbase[(13+q)*33 + g] = pkh2(e[1+2*q], e[2+2*q]);
      wvbase[24*33 + g] = pkh2(e[23], 0.f);                 // pair 24 = taps 48,(49=0)
    }
  }

  // ---- phase 3: aggregation (lane owns channels 4L..4L+3), tap-pairs; ags -> sA overlay ----
  // FULL unroll: 50 independent L2 gather loads -> deep ILP (this phase is latency-dominated)
  {
    int g_ = lane >> 1;
    int c0 = lane * 4;
    const int* gpp = gp_s + wv*64;
    float a0=0.f,a1=0.f,a2=0.f,a3=0.f;
    const char* xbb = (const char*)(x3h + (size_t)b*NPIX*256) + c0*2;
    #pragma unroll
    for (int p=0;p<25;p++){
      uint_t wu = wvbase[p*33 + g_];
      float w0 = h2lo(wu), w1 = h2hi(wu);
      int o0 = gpp[2*p], o1 = gpp[2*p+1];
      union { uint2 u; _Float16 h[4]; } d0, d1;
      d0.u = *(const uint2*)(xbb + o0);
      d1.u = *(const uint2*)(xbb + o1);
      a0 += w0*(float)d0.h[0] + w1*(float)d1.h[0];
      a1 += w0*(float)d0.h[1] + w1*(float)d1.h[1];
      a2 += w0*(float)d0.h[2] + w1*(float)d1.h[2];
      a3 += w0*(float)d0.h[3] + w1*(float)d1.h[3];
    }
    float* agw = (float*)(sA + wv*1280);          // overlay: own wave's sA, dead after phase 1
    *(float4*)&agw[c0] = make_float4(a0,a1,a2,a3);
  }
  __syncthreads();

  // ---- phase 4: position2, BLOCK-WIDE (thread = out channel c, 4 px); full unroll ----
  {
    int c = tid, g4 = c >> 3;
    const float* P2 = ws + P2T_OFF;
    const uint_t* P2H = (const uint_t*)ws + P2H_OFF;
    const float* ag0 = (const float*)(sA + 0*1280);
    const float* ag1 = (const float*)(sA + 1*1280);
    const float* ag2 = (const float*)(sA + 2*1280);
    const float* ag3 = (const float*)(sA + 3*1280);
    float r0=0.f, r1=0.f, r2=0.f, r3=0.f;
    #pragma unroll
    for (int i=0;i<8;i++){
      float pv = P2[i*256 + c];
      r0 += ag0[i*32 + g4] * pv;
      r1 += ag1[i*32 + g4] * pv;
      r2 += ag2[i*32 + g4] * pv;
      r3 += ag3[i*32 + g4] * pv;
    }
    #pragma unroll
    for (int p=0;p<25;p++){
      union { uint_t u; half2v h; } ph; ph.u = P2H[p*256 + c];
      union { uint_t u; half2v h; } w0, w1, w2, w3;
      w0.u = lgw[0*864 + p*33 + g4];
      w1.u = lgw[1*864 + p*33 + g4];
      w2.u = lgw[2*864 + p*33 + g4];
      w3.u = lgw[3*864 + p*33 + g4];
      r0 = __builtin_amdgcn_fdot2(w0.h, ph.h, r0, false);
      r1 = __builtin_amdgcn_fdot2(w1.h, ph.h, r1, false);
      r2 = __builtin_amdgcn_fdot2(w2.h, ph.h, r2, false);
      r3 = __builtin_amdgcn_fdot2(w3.h, ph.h, r3, false);
    }
    int pix0 = y*HW + xs4*4;
    *(float4*)(out + ((size_t)(b*256 + c))*NPIX + pix0) = make_float4(r0,r1,r2,r3);
  }
}

// ===================== launch =====================
extern "C" void kernel_launch(void* const* d_in, const int* in_sizes, int n_in,
                              void* d_out, int out_size, void* d_ws, size_t ws_size,
                              hipStream_t stream) {
  const float* x    = (const float*)d_in[0];
  const float* w1   = (const float*)d_in[1];
  const float* b1   = (const float*)d_in[2];
  const float* w2   = (const float*)d_in[3];
  const float* b2   = (const float*)d_in[4];
  const float* w3   = (const float*)d_in[5];
  const float* b3   = (const float*)d_in[6];
  const float* g1   = (const float*)d_in[7];
  const float* be1  = (const float*)d_in[8];
  const float* m1   = (const float*)d_in[9];
  const float* v1   = (const float*)d_in[10];
  const float* cw1  = (const float*)d_in[11];
  const float* g2   = (const float*)d_in[12];
  const float* be2  = (const float*)d_in[13];
  const float* m2   = (const float*)d_in[14];
  const float* v2   = (const float*)d_in[15];
  const float* cw2  = (const float*)d_in[16];
  const float* cw2b = (const float*)d_in[17];
  const float* p2   = (const float*)d_in[18];

  float* wsf = (float*)d_ws;
  _Float16* x3h = (_Float16*)((char*)d_ws + X3_BYTE_OFF);
  float* o = (float*)d_out;

  k0_prep<<<481, 256, 0, stream>>>(w1,b1,w2,b2,w3,b3,g1,be1,m1,v1,cw1,g2,be2,m2,v2,cw2,cw2b,p2,wsf);
  k1_proj<<<784, 256, 0, stream>>>(x, wsf, x3h);
  k2_fused<<<3136, 256, 0, stream>>>(wsf, x3h, o);
}